// Round 5
// baseline (335.473 us; speedup 1.0000x reference)
//
#include <hip/hip_runtime.h>
#include <hip/hip_bf16.h>

#define H 16
#define S 2048
#define DM 1024
#define HD 64
#define NB 2
#define LOG2E 1.4426950408889634f

typedef __attribute__((ext_vector_type(8))) short short8_t;
typedef __attribute__((ext_vector_type(4))) float f32x4;
typedef __attribute__((ext_vector_type(16))) float f32x16;

static __device__ __forceinline__ unsigned short f2bf(float f){
  union { float f; unsigned u; } x; x.f = f;
  unsigned r = x.u + 0x7fffu + ((x.u >> 16) & 1u);
  return (unsigned short)(r >> 16);
}

static __device__ __forceinline__ unsigned pk2(float a, float b){
  union { __hip_bfloat16 h; unsigned short u; } x, y;
  x.h = __hip_bfloat16(a); y.h = __hip_bfloat16(b);
  return (unsigned)x.u | ((unsigned)y.u << 16);
}

static __device__ __forceinline__ float ex2(float x){
#if __has_builtin(__builtin_amdgcn_exp2f)
  return __builtin_amdgcn_exp2f(x);
#else
  return exp2f(x);
#endif
}

// async global->LDS, 16B per lane. lds = wave-uniform base; HW adds lane*16.
static __device__ __forceinline__ void async16(void* lds, const void* g){
  __builtin_amdgcn_global_load_lds(
      (const __attribute__((address_space(1))) unsigned int*)g,
      (__attribute__((address_space(3))) unsigned int*)lds, 16, 0, 0);
}

// swap upper 32 lanes of x with lower 32 lanes of y (CDNA4 v_permlane32_swap_b32)
static __device__ __forceinline__ void pswap(unsigned &x, unsigned &y){
#if defined(__gfx950__) || defined(__AMDGCN__)
  asm("v_permlane32_swap_b32 %0, %1" : "+v"(x), "+v"(y));
#else
  unsigned sx = (unsigned)__shfl_xor((int)x, 32);
  unsigned sy = (unsigned)__shfl_xor((int)y, 32);
  bool hi = (threadIdx.x & 63) >= 32;
  unsigned nx = hi ? sy : x;
  unsigned ny = hi ? y : sx;
  x = nx; y = ny;
#endif
}

// ---------------- prep ----------------
// blocks [0,6144): q/k/v fp32->bf16 (8 elems/thread)
// blocks [6144,8192): mask -> TRANSPOSED bitmask mT[b][col64][row] u64 (64x64 tiles)
// blocks [8192,12288): 4x weight transpose+convert (32x32 tiles)
__global__ __launch_bounds__(256) void prep(const float* __restrict__ q, const float* __restrict__ k,
    const float* __restrict__ v, const int* __restrict__ mask,
    const float* __restrict__ Wq, const float* __restrict__ Wk, const float* __restrict__ Wv,
    const float* __restrict__ Wo,
    unsigned short* __restrict__ qb, unsigned short* __restrict__ kb, unsigned short* __restrict__ vb,
    unsigned short* __restrict__ WT, unsigned short* __restrict__ WoT,
    unsigned long long* __restrict__ mT){
  __shared__ float tt[32][33];
  __shared__ unsigned short ml[64][4];
  const int bid = blockIdx.x, tid = threadIdx.x;
  if (bid < 6144){
    const int w = bid >> 11;
    const int blk = bid & 2047;
    const float* src = (w==0)? q : (w==1)? k : v;
    unsigned short* dst = (w==0)? qb : (w==1)? kb : vb;
    size_t i = ((size_t)blk*256 + tid)*8;
    float4 x = *(const float4*)(src + i);
    float4 y = *(const float4*)(src + i + 4);
    ushort4 o1{f2bf(x.x),f2bf(x.y),f2bf(x.z),f2bf(x.w)};
    ushort4 o2{f2bf(y.x),f2bf(y.y),f2bf(y.z),f2bf(y.w)};
    *(ushort4*)(dst+i) = o1; *(ushort4*)(dst+i+4) = o2;
  } else if (bid < 8192){
    const int mt = bid - 6144;
    const int b2 = mt >> 10, rb = (mt >> 5) & 31, cb = mt & 31;
    const int r = tid >> 2, cq = tid & 3;
    const int* src = mask + ((size_t)b2*S + rb*64 + r)*S + cb*64 + cq*16;
    unsigned u = 0;
    #pragma unroll
    for (int j2=0;j2<4;j2++){
      int4 mm = *(const int4*)(src + j2*4);
      u |= (mm.x!=0 ? 1u:0u) << (j2*4);
      u |= (mm.y!=0 ? 1u:0u) << (j2*4+1);
      u |= (mm.z!=0 ? 1u:0u) << (j2*4+2);
      u |= (mm.w!=0 ? 1u:0u) << (j2*4+3);
    }
    ml[r][cq] = (unsigned short)u;
    __syncthreads();
    if (tid < 64){
      unsigned long long w64 = (unsigned long long)ml[tid][0]
        | ((unsigned long long)ml[tid][1] << 16)
        | ((unsigned long long)ml[tid][2] << 32)
        | ((unsigned long long)ml[tid][3] << 48);
      mT[((size_t)b2*32 + cb)*S + rb*64 + tid] = w64;
    }
  } else {
    const int wb = bid - 8192;
    const int widx = wb >> 10, t = wb & 1023;
    const float* W = (widx==0)? Wq : (widx==1)? Wk : (widx==2)? Wv : Wo;
    unsigned short* dst = (widx<3)? (WT + (size_t)widx*DM*DM) : WoT;
    const int tx = tid & 31, ty = tid >> 5;
    const int r0 = (t >> 5) * 32, c0 = (t & 31) * 32;
    #pragma unroll
    for (int i2=0;i2<32;i2+=8) tt[ty+i2][tx] = W[(size_t)(r0+ty+i2)*DM + c0+tx];
    __syncthreads();
    #pragma unroll
    for (int i2=0;i2<32;i2+=8) dst[(size_t)(c0+ty+i2)*DM + r0+tx] = f2bf(tt[tx][ty+i2]);
  }
}

// ---------------- fused QKV GEMM (m97-style: global_load_lds, dbuf, 1 barrier/K-step) ----------------
// 128x128 tile, BK=32, 4 waves (2x2). grid (24,32): p=blockIdx.x>>3 selects {Q,K,V}.
__global__ __launch_bounds__(256) void qkv_gemm(
    const unsigned short* __restrict__ qb, const unsigned short* __restrict__ kb,
    const unsigned short* __restrict__ vb2, const unsigned short* __restrict__ WT,
    const float* __restrict__ bq, const float* __restrict__ bk, const float* __restrict__ bv,
    unsigned short* __restrict__ Qp, unsigned short* __restrict__ Kp, unsigned short* __restrict__ VTp){
  __shared__ __align__(16) char Al[2][8192];
  __shared__ __align__(16) char Bl[2][8192];
  const int tid = threadIdx.x, lane = tid & 63, wv = tid >> 6;
  const int l15 = lane & 15, l4 = lane >> 4;
  const int wr = wv >> 1, wc = wv & 1;
  const int p = blockIdx.x >> 3;
  const int n0 = (blockIdx.x & 7) * 128;
  const int m0 = blockIdx.y * 128;
  const unsigned short* A = (p==0)? qb : (p==1)? kb : vb2;
  const unsigned short* Bt = WT + (size_t)blockIdx.x * 128 * DM;
  const float* bias = (p==0)? bq : (p==1)? bk : bv;

  f32x4 acc[4][4];
  #pragma unroll
  for (int i=0;i<4;i++)
    #pragma unroll
    for (int j=0;j<4;j++) acc[i][j] = (f32x4){0.f,0.f,0.f,0.f};

  // unit u (c=u>>6, l=u&63): row = c*16 + (l&15), k8 = l>>4; LDS offset = u*16 (linear)
  const char *ga0, *ga1, *gb0, *gb1;
  {
    int u = tid, c = u>>6, l = u&63;
    ga0 = (const char*)A  + ((size_t)(m0 + c*16 + (l&15))*DM + (l>>4)*8)*2;
    gb0 = (const char*)Bt + ((size_t)(c*16 + (l&15))*DM + (l>>4)*8)*2;
    u = tid + 256; c = u>>6; l = u&63;
    ga1 = (const char*)A  + ((size_t)(m0 + c*16 + (l&15))*DM + (l>>4)*8)*2;
    gb1 = (const char*)Bt + ((size_t)(c*16 + (l&15))*DM + (l>>4)*8)*2;
  }
  const int wb16 = wv*1024;

  auto stage = [&](int buf, int t){
    size_t o = (size_t)t*64;
    async16(&Al[buf][wb16],        ga0 + o);
    async16(&Al[buf][4096+wb16],   ga1 + o);
    async16(&Bl[buf][wb16],        gb0 + o);
    async16(&Bl[buf][4096+wb16],   gb1 + o);
  };

  stage(0, 0);
  __syncthreads();

  const bool sw = (p==2);
  const int NT = DM/32;
  int pb = 0;
  for (int t=0;t<NT;t++){
    if (t+1 < NT) stage(pb^1, t+1);
    short8_t av[4], bvv[4];
    #pragma unroll
    for (int i=0;i<4;i++) av[i]  = *(const short8_t*)(Al[pb] + (wr*4+i)*1024 + lane*16);
    #pragma unroll
    for (int j=0;j<4;j++) bvv[j] = *(const short8_t*)(Bl[pb] + (wc*4+j)*1024 + lane*16);
    __builtin_amdgcn_s_setprio(1);
    if (sw){
      #pragma unroll
      for (int i=0;i<4;i++)
        #pragma unroll
        for (int j=0;j<4;j++)
          acc[i][j] = __builtin_amdgcn_mfma_f32_16x16x32_bf16(bvv[j], av[i], acc[i][j], 0,0,0);
    } else {
      #pragma unroll
      for (int i=0;i<4;i++)
        #pragma unroll
        for (int j=0;j<4;j++)
          acc[i][j] = __builtin_amdgcn_mfma_f32_16x16x32_bf16(av[i], bvv[j], acc[i][j], 0,0,0);
    }
    __builtin_amdgcn_s_setprio(0);
    __syncthreads();   // drains vmcnt(0): buf pb^1 staged & visible; all reads of pb done
    pb ^= 1;
  }

  if (!sw){
    unsigned short* out = (p==0)? Qp : Kp;
    const float scl = (p==0)? 0.125f*LOG2E : 1.0f;
    #pragma unroll
    for (int i=0;i<4;i++)
      #pragma unroll
      for (int j=0;j<4;j++)
        #pragma unroll
        for (int jr=0;jr<4;jr++){
          int m = m0 + wr*64 + i*16 + l4*4 + jr;
          int n = n0 + wc*64 + j*16 + l15;
          float val = (acc[i][j][jr] + bias[n]) * scl;
          int b2 = m >> 11, s = m & (S-1), hh2 = n >> 6, d = n & 63;
          out[(((size_t)b2*H + hh2)*S + s)*HD + d] = f2bf(val);
        }
  } else {
    #pragma unroll
    for (int i=0;i<4;i++)
      #pragma unroll
      for (int j=0;j<4;j++)
        #pragma unroll
        for (int jr=0;jr<4;jr++){
          int n = n0 + wc*64 + j*16 + l4*4 + jr;
          int m = m0 + wr*64 + i*16 + l15;
          float val = acc[i][j][jr] + bias[n];
          int b2 = m >> 11, s = m & (S-1), hh2 = n >> 6, d = n & 63;
          VTp[(((size_t)b2*H + hh2)*HD + d)*S + s] = f2bf(val);
        }
  }
}

// ---------------- output GEMM: 128x64 tile, global_load_lds, fp32 out ----------------
__global__ __launch_bounds__(256) void out_gemm(const unsigned short* __restrict__ A,
    const unsigned short* __restrict__ WoT, const float* __restrict__ bo, float* __restrict__ out){
  __shared__ __align__(16) char Al[2][8192];
  __shared__ __align__(16) char Bl[2][4096];
  const int tid = threadIdx.x, lane = tid & 63, wv = tid >> 6;
  const int l15 = lane & 15, l4 = lane >> 4;
  const int wr = wv >> 1, wc = wv & 1;
  const int n0 = blockIdx.x * 64;
  const int m0 = blockIdx.y * 128;

  f32x4 acc[4][2];
  #pragma unroll
  for (int i=0;i<4;i++)
    #pragma unroll
    for (int j=0;j<2;j++) acc[i][j] = (f32x4){0.f,0.f,0.f,0.f};

  const char *ga0, *ga1, *gbp;
  {
    int u = tid, c = u>>6, l = u&63;
    ga0 = (const char*)A + ((size_t)(m0 + c*16 + (l&15))*DM + (l>>4)*8)*2;
    gbp = (const char*)WoT + ((size_t)(n0 + c*16 + (l&15))*DM + (l>>4)*8)*2;
    u = tid + 256; c = u>>6; l = u&63;
    ga1 = (const char*)A + ((size_t)(m0 + c*16 + (l&15))*DM + (l>>4)*8)*2;
  }
  const int wb16 = wv*1024;

  auto stage = [&](int buf, int t){
    size_t o = (size_t)t*64;
    async16(&Al[buf][wb16],      ga0 + o);
    async16(&Al[buf][4096+wb16], ga1 + o);
    async16(&Bl[buf][wb16],      gbp + o);
  };

  stage(0, 0);
  __syncthreads();

  const int NT = DM/32;
  int pb = 0;
  for (int t=0;t<NT;t++){
    if (t+1 < NT) stage(pb^1, t+1);
    short8_t av[4], bvv[2];
    #pragma unroll
    for (int i=0;i<4;i++) av[i]  = *(const short8_t*)(Al[pb] + (wr*4+i)*1024 + lane*16);
    #pragma unroll
    for (int j=0;j<2;j++) bvv[j] = *(const short8_t*)(Bl[pb] + (wc*2+j)*1024 + lane*16);
    __builtin_amdgcn_s_setprio(1);
    #pragma unroll
    for (int i=0;i<4;i++)
      #pragma unroll
      for (int j=0;j<2;j++)
        acc[i][j] = __builtin_amdgcn_mfma_f32_16x16x32_bf16(av[i], bvv[j], acc[i][j], 0,0,0);
    __builtin_amdgcn_s_setprio(0);
    __syncthreads();
    pb ^= 1;
  }

  #pragma unroll
  for (int i=0;i<4;i++)
    #pragma unroll
    for (int j=0;j<2;j++)
      #pragma unroll
      for (int jr=0;jr<4;jr++){
        int m = m0 + wr*64 + i*16 + l4*4 + jr;
        int n = n0 + wc*32 + j*16 + l15;
        out[(size_t)m*DM + n] = acc[i][j][jr] + bo[n];
      }
}

// ---------------- flash attention, 32x32 MFMA, global_load_lds staging ----------------
// 4 waves x 32 q-rows = 128 q/block; KV tiles of 64; log2-domain online softmax,
// defer-max THR=8; sums via ones-MFMA; P via cvt_pk + permlane32_swap; LDS-staged mask.
__global__ __launch_bounds__(256) void attn_fwd(const unsigned short* __restrict__ Qp,
    const unsigned short* __restrict__ Kp, const unsigned short* __restrict__ VTp,
    const unsigned long long* __restrict__ mT, unsigned short* __restrict__ X){
  __shared__ __align__(16) char sm[34816];   // K[2][8K] | V[2][8K] @16384 | M[2][1K] @32768
  const int tid = threadIdx.x, lane = tid & 63, wv = tid >> 6;
  const int q31 = lane & 31, h = lane >> 5;
  const int bh = blockIdx.y, b = bh >> 4, hh = bh & 15;
  const int q0 = blockIdx.x * 128;
  const int qrow = q0 + wv*32 + q31;

  const unsigned short* Qb = Qp + ((size_t)bh*S + qrow)*HD;
  short8_t qf[4];
  #pragma unroll
  for (int ks=0;ks<4;ks++) qf[ks] = *(const short8_t*)(Qb + ks*16 + h*8);

  short8_t ones8;
  #pragma unroll
  for (int j2=0;j2<8;j2++) ones8[j2] = (short)0x3F80;

  f32x16 o0, o1, aS;
  #pragma unroll
  for (int r=0;r<16;r++){ o0[r]=0.f; o1[r]=0.f; aS[r]=0.f; }
  float mrun = -3.0e38f;

  const char* KsrcB = (const char*)(Kp + (size_t)bh*S*HD);
  const char* VsrcB = (const char*)(VTp + (size_t)bh*HD*S);

  // staging sources: chunk c (=u>>6), l=u&63: kv=32*(c>>2)+(l&31), d=(c&3)*16+(l>>5)*8
  const char *kg0, *kg1, *vg0, *vg1, *mg;
  {
    int u = tid, c = u>>6, l = u&63;
    kg0 = KsrcB + ((size_t)(32*(c>>2) + (l&31))*HD + (c&3)*16 + (l>>5)*8)*2;
    vg0 = VsrcB + ((size_t)(32*(c>>2) + (l&31))*S  + (c&3)*16 + (l>>5)*8)*2;
    u = tid + 256; c = u>>6; l = u&63;
    kg1 = KsrcB + ((size_t)(32*(c>>2) + (l&31))*HD + (c&3)*16 + (l>>5)*8)*2;
    vg1 = VsrcB + ((size_t)(32*(c>>2) + (l&31))*S  + (c&3)*16 + (l>>5)*8)*2;
    mg  = (const char*)(mT + ((size_t)b*32)*S + q0) + lane*16;   // tile t: +t*16384
  }
  const int wb16 = wv*1024;

  auto stage = [&](int buf, int t){
    size_t ko = (size_t)t*8192, vo = (size_t)t*128;
    async16(&sm[buf*8192 + wb16],          kg0 + ko);
    async16(&sm[buf*8192 + 4096 + wb16],   kg1 + ko);
    async16(&sm[16384 + buf*8192 + wb16],        vg0 + vo);
    async16(&sm[16384 + buf*8192 + 4096 + wb16], vg1 + vo);
    if (wv == 0) async16(&sm[32768 + buf*1024], mg + (size_t)t*16384);
  };

  stage(0, 0);
  __syncthreads();

  const int NT = S/64;
  int pb = 0;
  for (int t=0; t<NT; ++t){
    if (t+1 < NT) stage(pb^1, t+1);
    const char* kb = sm + pb*8192;
    const char* vb = sm + 16384 + pb*8192;
    unsigned long long wcur = *(const unsigned long long*)(sm + 32768 + pb*1024 + (wv*32+q31)*8);

    f32x16 c0, c1;
    #pragma unroll
    for (int r=0;r<16;r++){ c0[r]=0.f; c1[r]=0.f; }
    __builtin_amdgcn_s_setprio(1);
    #pragma unroll
    for (int ks=0;ks<4;ks++){
      short8_t kf0 = *(const short8_t*)(kb + ks*1024 + lane*16);
      c0 = __builtin_amdgcn_mfma_f32_32x32x16_bf16(kf0, qf[ks], c0, 0,0,0);
      short8_t kf1 = *(const short8_t*)(kb + (4+ks)*1024 + lane*16);
      c1 = __builtin_amdgcn_mfma_f32_32x32x16_bf16(kf1, qf[ks], c1, 0,0,0);
    }
    __builtin_amdgcn_s_setprio(0);

    // max (log2 domain), defer-max THR=8
    float mf = c0[0];
    #pragma unroll
    for (int r=1;r<16;r++) mf = fmaxf(mf, c0[r]);
    #pragma unroll
    for (int r=0;r<16;r++) mf = fmaxf(mf, c1[r]);
    mf = fmaxf(mf, __shfl_xor(mf, 32));
    if (!__all(mf <= mrun + 8.0f)){
      float mnew = fmaxf(mrun, mf);
      float rs = ex2(mrun - mnew);
      mrun = mnew;
      #pragma unroll
      for (int r=0;r<16;r++){ o0[r]*=rs; o1[r]*=rs; }
      aS[0]*=rs;
    }

    // exp2 + bitmask zeroing
    unsigned long long wsh = wcur >> (4*h);
    unsigned mlo = (unsigned)wsh, mhi = (unsigned)(wsh >> 32);
    #pragma unroll
    for (int r=0;r<16;r++){
      const int bitc = (r&3) + 8*(r>>2);
      float e0 = ex2(c0[r] - mrun);
      float e1 = ex2(c1[r] - mrun);
      c0[r] = ((mlo >> bitc) & 1u) ? e0 : 0.f;
      c1[r] = ((mhi >> bitc) & 1u) ? e1 : 0.f;
    }

    // pack to bf16 pairs, redistribute into PV B-fragments via permlane32_swap
    unsigned w0[8], w1[8];
    #pragma unroll
    for (int m=0;m<8;m++){ w0[m] = pk2(c0[2*m], c0[2*m+1]); w1[m] = pk2(c1[2*m], c1[2*m+1]); }
    union Frag { short8_t s; unsigned w[4]; };
    Frag pf[4];
    { unsigned x=w0[0], y=w0[2]; pswap(x,y); pf[0].w[0]=x; pf[0].w[2]=y; }
    { unsigned x=w0[1], y=w0[3]; pswap(x,y); pf[0].w[1]=x; pf[0].w[3]=y; }
    { unsigned x=w0[4], y=w0[6]; pswap(x,y); pf[1].w[0]=x; pf[1].w[2]=y; }
    { unsigned x=w0[5], y=w0[7]; pswap(x,y); pf[1].w[1]=x; pf[1].w[3]=y; }
    { unsigned x=w1[0], y=w1[2]; pswap(x,y); pf[2].w[0]=x; pf[2].w[2]=y; }
    { unsigned x=w1[1], y=w1[3]; pswap(x,y); pf[2].w[1]=x; pf[2].w[3]=y; }
    { unsigned x=w1[4], y=w1[6]; pswap(x,y); pf[3].w[0]=x; pf[3].w[2]=y; }
    { unsigned x=w1[5], y=w1[7]; pswap(x,y); pf[3].w[1]=x; pf[3].w[3]=y; }

    __builtin_amdgcn_s_setprio(1);
    #pragma unroll
    for (int kvs=0;kvs<4;kvs++){
      aS = __builtin_amdgcn_mfma_f32_32x32x16_bf16(ones8, pf[kvs].s, aS, 0,0,0);
      short8_t vf0 = *(const short8_t*)(vb + kvs*1024 + lane*16);
      o0 = __builtin_amdgcn_mfma_f32_32x32x16_bf16(vf0, pf[kvs].s, o0, 0,0,0);
      short8_t vf1 = *(const short8_t*)(vb + (4+kvs)*1024 + lane*16);
      o1 = __builtin_amdgcn_mfma_f32_32x32x16_bf16(vf1, pf[kvs].s, o1, 0,0,0);
    }
    __builtin_amdgcn_s_setprio(0);

    __syncthreads();   // drains vmcnt: next buffers staged; all reads of pb done
    pb ^= 1;
  }

  // epilogue: normalize, stage rows in LDS (16B-slot XOR by row&7), coalesced store
  float inv = 1.0f / aS[0];
  const int ql = wv*32 + q31;
  #pragma unroll
  for (int m=0;m<8;m++){
    int d0 = ((2*m)&3) + 8*(m>>1) + 4*h;
    unsigned wa = pk2(o0[2*m]*inv, o0[2*m+1]*inv);
    *(unsigned*)(sm + ql*128 + (((d0>>3) ^ (ql&7))*16) + (d0&7)*2) = wa;
    int d1 = d0 + 32;
    unsigned wb2 = pk2(o1[2*m]*inv, o1[2*m+1]*inv);
    *(unsigned*)(sm + ql*128 + (((d1>>3) ^ (ql&7))*16) + (d1&7)*2) = wb2;
  }
  __syncthreads();
  #pragma unroll
  for (int it=0; it<4; it++){
    int u = it*256 + tid;
    int row = u>>3, cc = u&7;
    uint4 vvv = *(const uint4*)(sm + row*128 + cc*16);
    int g = cc ^ (row & 7);
    *(uint4*)(X + ((size_t)b*S + q0 + row)*DM + hh*HD + g*8) = vvv;
  }
}

// ---------------- launch ----------------
extern "C" void kernel_launch(void* const* d_in, const int* in_sizes, int n_in,
                              void* d_out, int out_size, void* d_ws, size_t ws_size,
                              hipStream_t stream){
  const float* query = (const float*)d_in[0];
  const float* key   = (const float*)d_in[1];
  const float* value = (const float*)d_in[2];
  const int*   mask  = (const int*)d_in[3];
  const float* Wq = (const float*)d_in[4];
  const float* bq = (const float*)d_in[5];
  const float* Wk = (const float*)d_in[6];
  const float* bk = (const float*)d_in[7];
  const float* Wv = (const float*)d_in[8];
  const float* bvp= (const float*)d_in[9];
  const float* Wo = (const float*)d_in[10];
  const float* bo = (const float*)d_in[11];

  const size_t NE = (size_t)NB*S*DM;       // 4194304
  const size_t WE = (size_t)DM*DM;         // 1048576

  char* w = (char*)d_ws;
  unsigned short* qb  = (unsigned short*)w; w += NE*2;
  unsigned short* kb  = (unsigned short*)w; w += NE*2;
  unsigned short* vb  = (unsigned short*)w; w += NE*2;
  unsigned short* WT  = (unsigned short*)w; w += 3*WE*2;
  unsigned short* WoT = (unsigned short*)w; w += WE*2;
  unsigned long long* mT = (unsigned long long*)w; w += (size_t)NB*32*S*8;
  unsigned short* Qp  = (unsigned short*)w; w += NE*2;
  unsigned short* Kp  = (unsigned short*)w; w += NE*2;
  unsigned short* VTp = (unsigned short*)w; w += NE*2;
  unsigned short* xb  = (unsigned short*)w; w += NE*2;

  prep<<<12288, 256, 0, stream>>>(query, key, value, mask, Wq, Wk, Wv, Wo,
                                  qb, kb, vb, WT, WoT, mT);
  qkv_gemm<<<dim3(24,32), 256, 0, stream>>>(qb, kb, vb, WT, bq, bk, bvp, Qp, Kp, VTp);
  attn_fwd<<<dim3(S/128, NB*H), 256, 0, stream>>>(Qp, Kp, VTp, mT, xb);
  out_gemm<<<dim3(DM/64, (NB*S)/128), 256, 0, stream>>>(xb, WoT, bo, (float*)d_out);
}